// Round 1
// baseline (421.217 us; speedup 1.0000x reference)
//
#include <hip/hip_runtime.h>
#include <hip/hip_bf16.h>
#include <stdint.h>

// Band-limited linear layer: y = x @ (mask*W)^T + bias
// x: [8192, 4096] f32, W: [4096, 4096] f32 (band |o-i|<=64), bias: [4096] f32.
//
// R2: W-resident persistent blocks, barrier-free streaming.
//  - Block owns 128 output cols; masked W tile (128x256) staged ONCE into LDS
//    as bf16 (64 KiB, XOR-swizzled 16B units -> no bank conflicts).
//  - 8 waves, each wave owns 16 rows x 128 cols per iteration; x A-fragments
//    loaded straight from global (no LDS, no x sharing needed), cvt in regs.
//  - NO __syncthreads in main loop -> no vmcnt(0) drains; rolling 1-iter-deep
//    register prefetch keeps ~16KB/wave of loads in flight.
//  - Grid 32 cb x 8 rg = 256 blocks = 1/CU, 8 iterations of 128 rows each.
//  - Band edges: k-clamped x addresses x zeroed W rows (exact: 0*finite=0).

constexpr int MROWS = 8192;
constexpr int NFEAT = 4096;
constexpr int KFEAT = 4096;
constexpr int DBAND = 64;

constexpr int BN    = 128;            // output cols per block
constexpr int KW    = 256;            // k-slice width = BN + 2*DBAND
constexpr int NS    = 8;              // k-steps of 32
constexpr int NW    = 8;              // waves per block
constexpr int WROWS = 16;             // rows per wave per iteration
constexpr int TROWS = NW * WROWS;     // 128 rows per block-iteration
constexpr int RPB   = 1024;           // rows per block
constexpr int NIT   = RPB / TROWS;    // 8 iterations

using bf16x8 = __attribute__((ext_vector_type(8))) short;  // 8 bf16 = 4 VGPRs
using f32x4  = __attribute__((ext_vector_type(4))) float;

__device__ __forceinline__ uint32_t pk2(float a, float b) {
    float2 t; t.x = a; t.y = b;
    __hip_bfloat162 h = __float22bfloat162_rn(t);
    union { __hip_bfloat162 h; uint32_t u; } cv;
    cv.h = h;
    return cv.u;  // low 16 = a, high 16 = b
}

__device__ __forceinline__ bf16x8 cvt8(const float4& a, const float4& b) {
    union { uint4 u; bf16x8 v; } r;
    r.u.x = pk2(a.x, a.y); r.u.y = pk2(a.z, a.w);
    r.u.z = pk2(b.x, b.y); r.u.w = pk2(b.z, b.w);
    return r.v;
}

__global__ __launch_bounds__(512)
void band_linear_kernel(const float* __restrict__ x,
                        const float* __restrict__ w,
                        const float* __restrict__ bias,
                        float* __restrict__ y)
{
    // 64 KiB: W tile [col][k] bf16, XOR-swizzled within each row (16B units)
    __shared__ short sW[BN * KW];

    const int tid  = threadIdx.x;
    const int lane = tid & 63;
    const int wv   = tid >> 6;          // wave 0..7
    const int l15  = lane & 15;
    const int lq   = lane >> 4;         // quarter 0..3

    const int cb   = blockIdx.x;        // col block 0..31
    const int rg   = blockIdx.y;        // row group 0..7
    const int col0 = cb * BN;
    const int i0   = col0 - DBAND;      // global k of j=0 (may be -64)

    // ---- per-step clamped k bases (uniform -> SGPRs); lq*8 added at use.
    // Clamp keeps all x loads in-bounds; W is zero wherever j is invalid.
    int sb[NS];
    #pragma unroll
    for (int s = 0; s < NS; ++s) {
        int b = i0 + s * 32;
        b = b < 0 ? 0 : b;
        b = b > (KFEAT - 32) ? (KFEAT - 32) : b;
        sb[s] = b;
    }

    // ---- issue iteration-0 x prefetch first (flies during W staging)
    const int row0 = rg * RPB + wv * WROWS + l15;
    const float* xp = x + (size_t)row0 * KFEAT;
    float4 px[2 * NS];
    #pragma unroll
    for (int s = 0; s < NS; ++s) {
        const float* p = xp + sb[s] + lq * 8;
        px[2 * s]     = *(const float4*)(p);
        px[2 * s + 1] = *(const float4*)(p + 4);
    }

    // ---- stage masked W tile into LDS (once per block)
    {
        const int wr   = tid & 127;       // tile col = output feature - col0
        const int ksel = tid >> 7;        // which 64-wide j chunk (0..3)
        const int gn   = col0 + wr;       // global output feature
        const int kbeg = i0 + ksel * 64;  // 64-aligned: fully valid or fully OOB
        short* drow    = &sW[wr * KW];
        const int swz  = (wr & 7) << 3;   // XOR swizzle of 16B-unit index
        if (kbeg >= 0 && kbeg < KFEAT) {
            const float* ws = w + (size_t)gn * KFEAT + kbeg;
            #pragma unroll
            for (int g = 0; g < 8; ++g) {
                float4 a = *(const float4*)(ws + g * 8);
                float4 b = *(const float4*)(ws + g * 8 + 4);
                const int k0 = kbeg + g * 8;
                #define MSK(v, kk) v = ((unsigned)((kk) - gn + DBAND) <= 2u * DBAND) ? v : 0.f
                MSK(a.x, k0 + 0); MSK(a.y, k0 + 1); MSK(a.z, k0 + 2); MSK(a.w, k0 + 3);
                MSK(b.x, k0 + 4); MSK(b.y, k0 + 5); MSK(b.z, k0 + 6); MSK(b.w, k0 + 7);
                #undef MSK
                uint4 p;
                p.x = pk2(a.x, a.y); p.y = pk2(a.z, a.w);
                p.z = pk2(b.x, b.y); p.w = pk2(b.z, b.w);
                *(uint4*)&drow[(ksel * 64 + g * 8) ^ swz] = p;
            }
        } else {
            const uint4 z = {0u, 0u, 0u, 0u};
            #pragma unroll
            for (int g = 0; g < 8; ++g)
                *(uint4*)&drow[(ksel * 64 + g * 8) ^ swz] = z;
        }
    }

    // ---- bias for this lane's 8 column fragments (invariant across iters)
    float bv[8];
    #pragma unroll
    for (int nf = 0; nf < 8; ++nf)
        bv[nf] = bias[col0 + nf * 16 + l15];

    __syncthreads();   // the ONLY barrier: sW ready, read-only hereafter

    f32x4 acc[8];

    #pragma unroll 1
    for (int it = 0; it < NIT; ++it) {
        #pragma unroll
        for (int nf = 0; nf < 8; ++nf) acc[nf] = (f32x4){0.f, 0.f, 0.f, 0.f};

        const float* xn = xp + (size_t)TROWS * KFEAT;  // next iteration's rows
        const bool pf = (it != NIT - 1);

        #pragma unroll
        for (int s = 0; s < NS; ++s) {
            // consume current fragment, then immediately re-issue its slot
            // for the next iteration (rolling prefetch, ~1 iter in flight)
            const bf16x8 af = cvt8(px[2 * s], px[2 * s + 1]);
            if (pf) {
                const float* p = xn + sb[s] + lq * 8;
                px[2 * s]     = *(const float4*)(p);
                px[2 * s + 1] = *(const float4*)(p + 4);
            }
            const int jb = s * 32 + lq * 8;
            #pragma unroll
            for (int nf = 0; nf < 8; ++nf) {
                const int jcol = nf * 16 + l15;
                const bf16x8 bf =
                    *(const bf16x8*)&sW[jcol * KW + (jb ^ ((jcol & 7) << 3))];
                acc[nf] = __builtin_amdgcn_mfma_f32_16x16x32_bf16(
                    af, bf, acc[nf], 0, 0, 0);
            }
        }

        // ---- epilogue: C layout col=lane&15, row=(lane>>4)*4+r
        const int grow = rg * RPB + it * TROWS + wv * WROWS + lq * 4;
        #pragma unroll
        for (int nf = 0; nf < 8; ++nf) {
            float* dst = y + (size_t)grow * NFEAT + (col0 + nf * 16 + l15);
            #pragma unroll
            for (int r = 0; r < 4; ++r)
                __builtin_nontemporal_store(acc[nf][r] + bv[nf],
                                            dst + (size_t)r * NFEAT);
        }
        xp = xn;
    }
}

extern "C" void kernel_launch(void* const* d_in, const int* in_sizes, int n_in,
                              void* d_out, int out_size, void* d_ws, size_t ws_size,
                              hipStream_t stream) {
    const float* x    = (const float*)d_in[0];
    const float* w    = (const float*)d_in[1];
    const float* bias = (const float*)d_in[2];
    // d_in[3] (mask) unused: band condition applied algebraically in staging.
    float* y = (float*)d_out;

    dim3 grid(NFEAT / BN, MROWS / RPB);  // 32 x 8 = 256 blocks (1 per CU)
    band_linear_kernel<<<grid, 512, 0, stream>>>(x, w, bias, y);
}